// Round 1
// baseline (624.718 us; speedup 1.0000x reference)
//
#include <hip/hip_runtime.h>
#include <hip/hip_bf16.h>

// Problem constants (from reference): B=1, L=4, C=128, H=240, W=480, LMAX=6, R=8
#define L_DIM 4
#define C_DIM 128
#define CH_DIM 64          // C/2
#define HW 115200          // 240*480
#define HW4 28800          // HW/4
#define R_DIM 8
#define K_DIM 36           // LMAX^2
#define WF_DIM 1312        // C*R + R*K = 1024 + 288
#define PIX_BLOCKS 450     // HW / 256

// ---------------------------------------------------------------------------
// Phase 1: ctx[l,c] = mean over H*W of x[l,c,:,:]
// One block per (l,c) pair -> 512 blocks of 256 threads, float4 loads.
// ---------------------------------------------------------------------------
__global__ __launch_bounds__(256) void mean_pool_kernel(
    const float* __restrict__ x, float* __restrict__ ctx) {
  const int b = blockIdx.x;  // l*128 + c
  const float4* xb = (const float4*)(x + (size_t)b * HW);
  float s = 0.0f;
  for (int i = threadIdx.x; i < HW4; i += 256) {
    float4 v = xb[i];
    s += (v.x + v.y) + (v.z + v.w);
  }
  // wave (64-lane) reduction
  #pragma unroll
  for (int off = 32; off > 0; off >>= 1) s += __shfl_down(s, off, 64);
  __shared__ float wsum[4];
  const int wid = threadIdx.x >> 6;
  if ((threadIdx.x & 63) == 0) wsum[wid] = s;
  __syncthreads();
  if (threadIdx.x == 0) {
    float t = (wsum[0] + wsum[1]) + (wsum[2] + wsum[3]);
    ctx[b] = t * (1.0f / (float)HW);
  }
}

// ---------------------------------------------------------------------------
// Phase 2: hypernet. Single block, 256 threads. Produces
//   gcoeff[l,c,k] = gain[c] * sum_r W1[l,c,r] * W2[l,r,k]
// where [W1|W2] = silu(ctx@Wa+ba)@Wb + bb.
// ---------------------------------------------------------------------------
__global__ __launch_bounds__(256) void hypernet_kernel(
    const float* __restrict__ ctx, const float* __restrict__ Wa,
    const float* __restrict__ ba, const float* __restrict__ Wb,
    const float* __restrict__ bb, const float* __restrict__ gain,
    float* __restrict__ gcoeff) {
  __shared__ float sctx[L_DIM * C_DIM];    // 512
  __shared__ float sh[L_DIM * CH_DIM];     // 256
  __shared__ float swf[L_DIM * WF_DIM];    // 5248
  const int tid = threadIdx.x;

  // load ctx
  sctx[tid] = ctx[tid];
  sctx[tid + 256] = ctx[tid + 256];
  __syncthreads();

  // h = silu(ctx @ Wa + ba): 4*64 = 256 outputs, one per thread
  {
    const int l = tid >> 6;        // /64
    const int j = tid & 63;
    float acc = ba[j];
    #pragma unroll 8
    for (int c = 0; c < C_DIM; ++c) acc += sctx[l * C_DIM + c] * Wa[c * CH_DIM + j];
    // silu(x) = x * sigmoid(x)
    sh[tid] = acc / (1.0f + __expf(-acc));
  }
  __syncthreads();

  // wf = h @ Wb + bb: 4*1312 outputs
  for (int o = tid; o < L_DIM * WF_DIM; o += 256) {
    const int l = o / WF_DIM;
    const int oo = o - l * WF_DIM;
    float acc = bb[oo];
    #pragma unroll 8
    for (int j = 0; j < CH_DIM; ++j) acc += sh[l * CH_DIM + j] * Wb[j * WF_DIM + oo];
    swf[o] = acc;
  }
  __syncthreads();

  // gcoeff[l,c,k] = gain[c] * sum_r W1[l,c,r]*W2[l,r,k]
  for (int i = tid; i < L_DIM * C_DIM * K_DIM; i += 256) {
    const int l = i / (C_DIM * K_DIM);
    const int r2 = i - l * (C_DIM * K_DIM);
    const int c = r2 / K_DIM;
    const int k = r2 - c * K_DIM;
    const float* w1 = &swf[l * WF_DIM + c * R_DIM];
    const float* w2 = &swf[l * WF_DIM + C_DIM * R_DIM + k];
    float acc = 0.0f;
    #pragma unroll
    for (int r = 0; r < R_DIM; ++r) acc += w1[r] * w2[r * K_DIM];
    gcoeff[i] = gain[c] * acc;
  }
}

// ---------------------------------------------------------------------------
// Phase 3: out[l,c,p] = x[l,c,p] + dot(gcoeff[l,c,:], Y[:,p])
// One thread per pixel p; thread keeps Y[:,p] in 36 VGPRs and loops over
// all 128 channels. gcoeff accesses are wave-uniform -> scalar loads.
// Grid: L * (HW/256) = 1800 blocks.
// ---------------------------------------------------------------------------
__global__ __launch_bounds__(256) void bias_add_kernel(
    const float* __restrict__ x, const float* __restrict__ Y,
    const float* __restrict__ gcoeff, float* __restrict__ out) {
  const int b = blockIdx.x;
  const int l = b / PIX_BLOCKS;
  const int p = (b - l * PIX_BLOCKS) * 256 + threadIdx.x;

  float y[K_DIM];
  #pragma unroll
  for (int k = 0; k < K_DIM; ++k) y[k] = Y[k * HW + p];

  const float* gc = gcoeff + l * (C_DIM * K_DIM);
  const float* xl = x + (size_t)l * C_DIM * HW + p;
  float* ol = out + (size_t)l * C_DIM * HW + p;

  #pragma unroll 4
  for (int c = 0; c < C_DIM; ++c) {
    const float* g = gc + c * K_DIM;
    float acc = 0.0f;
    #pragma unroll
    for (int k = 0; k < K_DIM; ++k) acc += g[k] * y[k];
    ol[(size_t)c * HW] = xl[(size_t)c * HW] + acc;
  }
}

// ---------------------------------------------------------------------------
extern "C" void kernel_launch(void* const* d_in, const int* in_sizes, int n_in,
                              void* d_out, int out_size, void* d_ws, size_t ws_size,
                              hipStream_t stream) {
  const float* x    = (const float*)d_in[0];
  const float* Wa   = (const float*)d_in[1];
  const float* ba   = (const float*)d_in[2];
  const float* Wb   = (const float*)d_in[3];
  const float* bb   = (const float*)d_in[4];
  const float* gain = (const float*)d_in[5];
  const float* Y    = (const float*)d_in[6];
  float* out = (float*)d_out;

  float* ctx    = (float*)d_ws;                  // 512 floats
  float* gcoeff = (float*)((char*)d_ws + 4096);  // 18432 floats (~74 KB)

  mean_pool_kernel<<<L_DIM * C_DIM, 256, 0, stream>>>(x, ctx);
  hypernet_kernel<<<1, 256, 0, stream>>>(ctx, Wa, ba, Wb, bb, gain, gcoeff);
  bias_add_kernel<<<L_DIM * PIX_BLOCKS, 256, 0, stream>>>(x, Y, gcoeff, out);
}

// Round 2
// 476.836 us; speedup vs baseline: 1.3101x; 1.3101x over previous
//
#include <hip/hip_runtime.h>
#include <hip/hip_bf16.h>

// Problem constants: B=1, L=4, C=128, H=240, W=480, LMAX=6, R=8
#define L_DIM 4
#define C_DIM 128
#define CH_DIM 64          // C/2
#define HW 115200          // 240*480
#define HW4 28800          // HW/4
#define R_DIM 8
#define K_DIM 36           // LMAX^2
#define WF_DIM 1312        // C*R + R*K = 1024 + 288
#define WF_TOT 5248        // L * WF_DIM
#define PBLK 225           // HW / 512 (512 pixels per block, 2 per thread)

typedef __attribute__((ext_vector_type(16))) float vf16;
typedef __attribute__((ext_vector_type(4)))  float vf4;

// ---------------------------------------------------------------------------
// K1: ctx[l,c] = mean over HW of x[l,c,:,:]. One block per (l,c): 512 blocks.
// 4-deep load ILP to keep ~32KB/CU in flight (Little's law for ~900cy HBM lat).
// ---------------------------------------------------------------------------
__global__ __launch_bounds__(256) void mean_pool_kernel(
    const float* __restrict__ x, float* __restrict__ ctx) {
  const int b = blockIdx.x;  // l*128 + c
  const float4* xb = (const float4*)(x + (size_t)b * HW);
  float s0 = 0.f, s1 = 0.f, s2 = 0.f, s3 = 0.f;
  int i = threadIdx.x;
  #pragma unroll 1
  for (; i + 768 < HW4; i += 1024) {
    float4 a = xb[i];
    float4 bq = xb[i + 256];
    float4 c = xb[i + 512];
    float4 d = xb[i + 768];
    s0 += (a.x + a.y) + (a.z + a.w);
    s1 += (bq.x + bq.y) + (bq.z + bq.w);
    s2 += (c.x + c.y) + (c.z + c.w);
    s3 += (d.x + d.y) + (d.z + d.w);
  }
  for (; i < HW4; i += 256) {
    float4 a = xb[i];
    s0 += (a.x + a.y) + (a.z + a.w);
  }
  float s = (s0 + s1) + (s2 + s3);
  #pragma unroll
  for (int off = 32; off > 0; off >>= 1) s += __shfl_down(s, off, 64);
  __shared__ float wsum[4];
  if ((threadIdx.x & 63) == 0) wsum[threadIdx.x >> 6] = s;
  __syncthreads();
  if (threadIdx.x == 0) {
    float t = (wsum[0] + wsum[1]) + (wsum[2] + wsum[3]);
    ctx[b] = t * (1.0f / (float)HW);
  }
}

// ---------------------------------------------------------------------------
// K2: hypernet. 21 blocks x 256 threads. Each block recomputes h (cheap, L2-hit
// Wa), then computes a 256-output slice of wf = h@Wb + bb. gain is folded into
// the W1 portion (oo < 1024): wf[l, c*8+r] *= gain[c].
// ---------------------------------------------------------------------------
__global__ __launch_bounds__(256) void hyper_kernel(
    const float* __restrict__ ctx, const float* __restrict__ Wa,
    const float* __restrict__ ba, const float* __restrict__ Wb,
    const float* __restrict__ bb, const float* __restrict__ gain,
    float* __restrict__ wf) {
  __shared__ float sctx[L_DIM * C_DIM];  // 512
  __shared__ float sh[L_DIM * CH_DIM];   // 256
  const int tid = threadIdx.x;
  sctx[tid] = ctx[tid];
  sctx[tid + 256] = ctx[tid + 256];
  __syncthreads();
  {
    const int l = tid >> 6, j = tid & 63;
    float acc = ba[j];
    #pragma unroll 16
    for (int c = 0; c < C_DIM; ++c) acc += sctx[l * C_DIM + c] * Wa[c * CH_DIM + j];
    sh[tid] = acc / (1.0f + __expf(-acc));  // silu
  }
  __syncthreads();
  const int o = blockIdx.x * 256 + tid;
  if (o < WF_TOT) {
    const int l = o / WF_DIM;
    const int oo = o - l * WF_DIM;
    float acc = bb[oo];
    #pragma unroll 16
    for (int j = 0; j < CH_DIM; ++j) acc += sh[l * CH_DIM + j] * Wb[j * WF_DIM + oo];
    if (oo < C_DIM * R_DIM) acc *= gain[oo >> 3];
    wf[o] = acc;
  }
}

// ---------------------------------------------------------------------------
// K3: out[l,c,p] = x[l,c,p] + sum_r gW1[l,c,r] * z[r,p],
//     z[r,p] = sum_k W2[l,r,k] * Y[k,p]   (computed in prologue, 2 px/thread)
// All W1/W2 operands delivered via inline-asm s_load -> SGPR FMA operands.
// Grid: L * PBLK * 2 channel-halves = 1800 blocks.
// ---------------------------------------------------------------------------
__global__ __launch_bounds__(256) void bias_add_kernel(
    const float* __restrict__ x, const float* __restrict__ Y,
    const float* __restrict__ wf, float* __restrict__ out) {
  const int b = blockIdx.x;
  const int half = b & 1;
  const int t = b >> 1;          // [0, 900)
  const int l = t / PBLK;
  const int pb = t - l * PBLK;
  const int p = pb * 512 + threadIdx.x * 2;

  // ---- prologue: z[r] for both pixels ----
  float z0[R_DIM], z1[R_DIM];
  {
    float2 y[K_DIM];
    #pragma unroll
    for (int k = 0; k < K_DIM; ++k) y[k] = *(const float2*)(Y + k * HW + p);
    const float* w2base = wf + l * WF_DIM + C_DIM * R_DIM;
    #pragma unroll
    for (int r = 0; r < R_DIM; ++r) {
      vf16 a, bq; vf4 cq;
      const float* wp = w2base + r * K_DIM;
      asm volatile(
          "s_load_dwordx16 %0, %3, 0x0\n\t"
          "s_load_dwordx16 %1, %3, 0x40\n\t"
          "s_load_dwordx4  %2, %3, 0x80\n\t"
          "s_waitcnt lgkmcnt(0)"
          : "=&s"(a), "=&s"(bq), "=&s"(cq)
          : "s"(wp));
      float za = 0.f, zb = 0.f;
      #pragma unroll
      for (int k = 0; k < 16; ++k) { za += a[k] * y[k].x;      zb += a[k] * y[k].y; }
      #pragma unroll
      for (int k = 0; k < 16; ++k) { za += bq[k] * y[16 + k].x; zb += bq[k] * y[16 + k].y; }
      #pragma unroll
      for (int k = 0; k < 4; ++k)  { za += cq[k] * y[32 + k].x; zb += cq[k] * y[32 + k].y; }
      z0[r] = za; z1[r] = zb;
    }
  }

  // ---- main loop: 64 channels, 8 at a time (gW1 rows via one s_load group) ----
  const float* w1base = wf + l * WF_DIM + half * (64 * R_DIM);
  const size_t xoff = (size_t)l * C_DIM * HW + (size_t)half * 64 * HW + (size_t)p;
  const float* xp = x + xoff;
  float* op = out + xoff;

  #pragma unroll 1
  for (int cc = 0; cc < 64; cc += 8) {
    vf16 w0, w1, w2, w3;  // 64 floats = gW1 rows for channels cc..cc+7
    const float* wp = w1base + cc * R_DIM;
    asm volatile(
        "s_load_dwordx16 %0, %4, 0x0\n\t"
        "s_load_dwordx16 %1, %4, 0x40\n\t"
        "s_load_dwordx16 %2, %4, 0x80\n\t"
        "s_load_dwordx16 %3, %4, 0xC0\n\t"
        "s_waitcnt lgkmcnt(0)"
        : "=&s"(w0), "=&s"(w1), "=&s"(w2), "=&s"(w3)
        : "s"(wp));
    float wl[64];
    #pragma unroll
    for (int k = 0; k < 16; ++k) {
      wl[k] = w0[k]; wl[16 + k] = w1[k]; wl[32 + k] = w2[k]; wl[48 + k] = w3[k];
    }
    #pragma unroll
    for (int c8 = 0; c8 < 8; ++c8) {
      float a0 = 0.f, a1 = 0.f;
      #pragma unroll
      for (int r = 0; r < R_DIM; ++r) {
        const float wv = wl[c8 * 8 + r];
        a0 += wv * z0[r];
        a1 += wv * z1[r];
      }
      const size_t co = (size_t)(cc + c8) * HW;
      float2 xv = *(const float2*)(xp + co);
      float2 ov;
      ov.x = xv.x + a0;
      ov.y = xv.y + a1;
      *(float2*)(op + co) = ov;
    }
  }
}

// ---------------------------------------------------------------------------
extern "C" void kernel_launch(void* const* d_in, const int* in_sizes, int n_in,
                              void* d_out, int out_size, void* d_ws, size_t ws_size,
                              hipStream_t stream) {
  const float* x    = (const float*)d_in[0];
  const float* Wa   = (const float*)d_in[1];
  const float* ba   = (const float*)d_in[2];
  const float* Wb   = (const float*)d_in[3];
  const float* bb   = (const float*)d_in[4];
  const float* gain = (const float*)d_in[5];
  const float* Y    = (const float*)d_in[6];
  float* out = (float*)d_out;

  float* ctx = (float*)d_ws;                   // 512 floats
  float* wf  = (float*)((char*)d_ws + 4096);   // 5248 floats

  mean_pool_kernel<<<L_DIM * C_DIM, 256, 0, stream>>>(x, ctx);
  hyper_kernel<<<21, 256, 0, stream>>>(ctx, Wa, ba, Wb, bb, gain, wf);
  bias_add_kernel<<<L_DIM * PBLK * 2, 256, 0, stream>>>(x, Y, wf, out);
}